// Round 2
// baseline (4473.209 us; speedup 1.0000x reference)
//
#include <hip/hip_runtime.h>

typedef __bf16 bf16x8 __attribute__((ext_vector_type(8)));
typedef float  f32x4  __attribute__((ext_vector_type(4)));
typedef unsigned long long u64;
typedef u64 u64x2 __attribute__((ext_vector_type(2)));

#define AGENT __HIP_MEMORY_SCOPE_AGENT

__device__ __forceinline__ float fast_tanh(float x) {
    float e = __expf(2.0f * x);
    return 1.0f - 2.0f * __builtin_amdgcn_rcpf(e + 1.0f);
}

// Raw barrier: drain ONLY LDS ops (cross-wave hread/hist visibility); global
// loads/stores stay in flight across the barrier.
__device__ __forceinline__ void lds_barrier() {
    asm volatile("s_waitcnt lgkmcnt(0)" ::: "memory");
    __builtin_amdgcn_s_barrier();
}

// SE-scope (L1-bypass, L2-served) 16B poll load. Plain stores by a CU on the
// same XCD are visible here via the shared (writeback) L2 — no L3/HBM trip.
// vmcnt(0) is safe: polling waves have no other outstanding vmem by design.
__device__ __forceinline__ u64x2 poll_ld(const u64* p) {
    u64x2 v;
    asm volatile("global_load_dwordx4 %0, %1, off sc0\n\t"
                 "s_waitcnt vmcnt(0)"
                 : "=v"(v) : "v"(p));
    return v;
}

// ---------------------------------------------------------------------------
// Kernel 1: xproj = x @ Wih^T + bih -> fp32 into d_out's states region.
// ---------------------------------------------------------------------------
__global__ __launch_bounds__(256) void xproj_gemm_kernel(
    const float* __restrict__ x, const float* __restrict__ Wih,
    const float* __restrict__ bih, float* __restrict__ out)
{
    __shared__ __bf16 Ash[64][72];
    __shared__ __bf16 Bsh[64][72];

    const int tid  = threadIdx.x;
    const int wave = tid >> 6, lane = tid & 63;
    const int col  = lane & 15, kq = lane >> 4;
    const int bt0  = blockIdx.x * 64;
    const int h0   = blockIdx.y * 64;

    f32x4 acc[4];
#pragma unroll
    for (int nt = 0; nt < 4; ++nt) acc[nt] = (f32x4){0.f, 0.f, 0.f, 0.f};

    const int r  = tid >> 2;
    const int cb = (tid & 3) * 16;

    for (int k0 = 0; k0 < 512; k0 += 64) {
        const float* ax = x   + (size_t)(bt0 + r) * 512 + k0 + cb;
        const float* bx = Wih + (size_t)(h0  + r) * 512 + k0 + cb;
#pragma unroll
        for (int j = 0; j < 4; ++j) {
            const float4 av = ((const float4*)ax)[j];
            const float4 bv = ((const float4*)bx)[j];
            const int c = cb + 4 * j;
            Ash[r][c+0]=(__bf16)av.x; Ash[r][c+1]=(__bf16)av.y;
            Ash[r][c+2]=(__bf16)av.z; Ash[r][c+3]=(__bf16)av.w;
            Bsh[r][c+0]=(__bf16)bv.x; Bsh[r][c+1]=(__bf16)bv.y;
            Bsh[r][c+2]=(__bf16)bv.z; Bsh[r][c+3]=(__bf16)bv.w;
        }
        __syncthreads();
#pragma unroll
        for (int kt = 0; kt < 2; ++kt) {
            bf16x8 a = *(const bf16x8*)&Ash[wave * 16 + col][kt * 32 + kq * 8];
#pragma unroll
            for (int nt = 0; nt < 4; ++nt) {
                bf16x8 bb = *(const bf16x8*)&Bsh[nt * 16 + col][kt * 32 + kq * 8];
                acc[nt] = __builtin_amdgcn_mfma_f32_16x16x32_bf16(a, bb, acc[nt], 0, 0, 0);
            }
        }
        __syncthreads();
    }
#pragma unroll
    for (int nt = 0; nt < 4; ++nt) {
        const float bv = bih[h0 + nt * 16 + col];
#pragma unroll
        for (int reg = 0; reg < 4; ++reg) {
            const int m = bt0 + wave * 16 + kq * 4 + reg;
            out[(size_t)m * 512 + h0 + nt * 16 + col] = acc[nt][reg] + bv;
        }
    }
}

// ---------------------------------------------------------------------------
// Kernel 2: recurrence. 128 blocks = 32 batches x 4 weight-stationary slices.
// Fast path: XCD-local mailbox (plain stores + sc0 loads, stays in L2).
// Safety net: wave0 posts the whole block's h(t-1) to an agent-scope global
// mailbox each step; pollers fall back to it after 16 local spins — so a
// changed blockIdx->XCD mapping degrades speed, never correctness.
// ---------------------------------------------------------------------------
__global__ __launch_bounds__(256) void lagrange_rnn_kernel(
    const float* __restrict__ Whh, const float* __restrict__ bhh,
    const float* __restrict__ kern, float* __restrict__ out,
    u64* __restrict__ mboxG, u64* __restrict__ mboxL)
{
    const int id   = blockIdx.x;                 // 0..127
    const int b    = (id & 7) + ((id >> 5) << 3);// batch 0..31 (group on one XCD)
    const int p    = (id >> 3) & 3;              // slice member 0..3
    const int tid  = threadIdx.x;
    const int wave = tid >> 6, lane = tid & 63;
    const int col  = lane & 15, kq = lane >> 4;

    __shared__ float  hist[4][512];    // circular h history, fp32
    __shared__ __bf16 hread[2][512];   // parity double-buffered MFMA A operand
    __shared__ float  xpb[2][128];     // parity double-buffered xp (wave0-fed)

    for (int i = tid; i < 2048; i += 256) ((float*)hist)[i] = 0.f;
    for (int i = tid; i < 512;  i += 256) { hread[0][i] = (__bf16)0.f; hread[1][i] = (__bf16)0.f; }

    // --- weight fragments, K-reordered: wf[j] <-> global K-tile (4p+j)&15
    const int hA = p * 128 + wave * 32 + col;
    const int hB = hA + 16;
    bf16x8 wf0[16], wf1[16];
#pragma unroll
    for (int j = 0; j < 16; ++j) {
        const int ktg = ((j + 4 * p) & 15) * 32 + kq * 8;
        const float* s0 = Whh + (size_t)hA * 512 + ktg;
        const float* s1 = Whh + (size_t)hB * 512 + ktg;
        const float4 a0 = *(const float4*)s0, a1 = *(const float4*)(s0 + 4);
        const float4 b0 = *(const float4*)s1, b1 = *(const float4*)(s1 + 4);
        bf16x8 w;
        w[0]=(__bf16)a0.x; w[1]=(__bf16)a0.y; w[2]=(__bf16)a0.z; w[3]=(__bf16)a0.w;
        w[4]=(__bf16)a1.x; w[5]=(__bf16)a1.y; w[6]=(__bf16)a1.z; w[7]=(__bf16)a1.w;
        wf0[j] = w;
        w[0]=(__bf16)b0.x; w[1]=(__bf16)b0.y; w[2]=(__bf16)b0.z; w[3]=(__bf16)b0.w;
        w[4]=(__bf16)b1.x; w[5]=(__bf16)b1.y; w[6]=(__bf16)b1.z; w[7]=(__bf16)b1.w;
        wf1[j] = w;
    }
    const float k0 = kern[0], k1 = kern[1], k2 = kern[2], k3 = kern[3];
    const float bA = bhh[hA], bB = bhh[hB];
    float* stA = out + (size_t)b * 1024 * 512 + hA;
    // wave0's xp source: the block's contiguous 128-slice [p*128, p*128+128)
    const float* xsrc = out + (size_t)b * 1024 * 512 + p * 128 + lane * 2;
    const int peer = (p + wave) & 3;              // waves 1..3 poll this peer
    const int j0 = peer * 128 + lane * 2;
    const bool comp = (lane < 16);
    const int abase = p * 128 + kq * 8;           // j-th A addr = (abase + 32j) & 511
    const int xslot = wave * 32 + col;            // xp LDS slot for this comp lane

    if (wave == 0) {                              // preload xp(0)
        const float2 x0 = *(const float2*)xsrc;
        xpb[0][lane * 2] = x0.x; xpb[0][lane * 2 + 1] = x0.y;
    }
    __syncthreads();

    for (int t = 0; t < 1024; ++t) {
        const int rb = t & 1, wb = rb ^ 1;
        const int rt = t & 3;
        const int rm1 = (t + 3) & 3, rm2 = (t + 2) & 3, rm3 = (t + 1) & 3;

        // --- wave0: issue xp(t+1) prefetch (drained only at bottom deposit)
        float2 nx = {0.f, 0.f};
        if (wave == 0) nx = *(const float2*)(xsrc + (size_t)(t + 1) * 512);

        lds_barrier();   // barA: prev-step LDS deposits visible (lgkm only)

        // --- phase 1: own-K MFMAs (j=0..3) — operands produced locally last step
        f32x4 acc0 = (f32x4){0,0,0,0}, acc1 = (f32x4){0,0,0,0};
#pragma unroll
        for (int j = 0; j < 4; ++j) {
            bf16x8 a = *(const bf16x8*)&hread[rb][(abase + 32 * j) & 511];
            acc0 = __builtin_amdgcn_mfma_f32_16x16x32_bf16(a, wf0[j], acc0, 0, 0, 0);
            acc1 = __builtin_amdgcn_mfma_f32_16x16x32_bf16(a, wf1[j], acc1, 0, 0, 0);
        }

        if (wave == 0) {
            // --- global fallback post: whole block's h(t-1), tag t, parity rb
            u64* mg = mboxG + (size_t)(((b << 1) | rb) * 4 + p) * 128;
            union { float f; unsigned u; } a0, a1;
            a0.f = hist[rm1][p * 128 + lane * 2];
            a1.f = hist[rm1][p * 128 + lane * 2 + 1];
            const u64 tg = (u64)(unsigned)t << 32;
            __hip_atomic_store(&mg[lane * 2],     tg | a0.u, __ATOMIC_RELAXED, AGENT);
            __hip_atomic_store(&mg[lane * 2 + 1], tg | a1.u, __ATOMIC_RELAXED, AGENT);
        } else if (t) {
            // --- poll peer's h(t-1) from the XCD-local mailbox (L2-resident)
            const unsigned want = (unsigned)t;
            const u64* ml = mboxL + (size_t)(((b << 1) | rb) * 4 + peer) * 128 + lane * 2;
            const u64* mg = mboxG + (size_t)(((b << 1) | rb) * 4 + peer) * 128 + lane * 2;
            u64x2 v = poll_ld(ml);
            int spins = 0;
            while ((unsigned)(v[0] >> 32) != want || (unsigned)(v[1] >> 32) != want) {
                if (++spins > 16) {
                    const u64 g0 = __hip_atomic_load(&mg[0], __ATOMIC_RELAXED, AGENT);
                    const u64 g1 = __hip_atomic_load(&mg[1], __ATOMIC_RELAXED, AGENT);
                    if ((unsigned)(g0 >> 32) == want && (unsigned)(g1 >> 32) == want) {
                        v[0] = g0; v[1] = g1; break;
                    }
                }
                v = poll_ld(ml);
            }
            union { unsigned u; float f; } d0, d1;
            d0.u = (unsigned)v[0]; d1.u = (unsigned)v[1];
            const float q0 = k1 * hist[rm2][j0]     + k2 * hist[rm3][j0]     + k3 * hist[rt][j0];
            const float q1 = k1 * hist[rm2][j0 + 1] + k2 * hist[rm3][j0 + 1] + k3 * hist[rt][j0 + 1];
            hread[rb][j0]     = (__bf16)(q0 + k0 * d0.f);
            hread[rb][j0 + 1] = (__bf16)(q1 + k0 * d1.f);
            hist[rm1][j0]     = d0.f;
            hist[rm1][j0 + 1] = d1.f;
        }

        lds_barrier();   // barB: poll deposits visible (lgkm only)

        // --- xp read + Lagrange partial for own hread(t+1)
        float xAv = 0.f, xBv = 0.f, ppA = 0.f, ppB = 0.f;
        if (comp) {
            xAv = xpb[rb][xslot];
            xBv = xpb[rb][xslot + 16];
            ppA = k1 * hist[rm1][hA] + k2 * hist[rm2][hA] + k3 * hist[rm3][hA];
            ppB = k1 * hist[rm1][hB] + k2 * hist[rm2][hB] + k3 * hist[rm3][hB];
        }

        // --- phase 2: peer-K MFMAs (j=4..15), 6 fresh chains (4-deep) for ILP
        f32x4 c0a = (f32x4){0,0,0,0}, c0b = (f32x4){0,0,0,0}, c0c = (f32x4){0,0,0,0};
        f32x4 c1a = (f32x4){0,0,0,0}, c1b = (f32x4){0,0,0,0}, c1c = (f32x4){0,0,0,0};
#pragma unroll
        for (int j = 4; j < 8; ++j) {
            bf16x8 a = *(const bf16x8*)&hread[rb][(abase + 32 * j) & 511];
            c0a = __builtin_amdgcn_mfma_f32_16x16x32_bf16(a, wf0[j], c0a, 0, 0, 0);
            c1a = __builtin_amdgcn_mfma_f32_16x16x32_bf16(a, wf1[j], c1a, 0, 0, 0);
        }
#pragma unroll
        for (int j = 8; j < 12; ++j) {
            bf16x8 a = *(const bf16x8*)&hread[rb][(abase + 32 * j) & 511];
            c0b = __builtin_amdgcn_mfma_f32_16x16x32_bf16(a, wf0[j], c0b, 0, 0, 0);
            c1b = __builtin_amdgcn_mfma_f32_16x16x32_bf16(a, wf1[j], c1b, 0, 0, 0);
        }
#pragma unroll
        for (int j = 12; j < 16; ++j) {
            bf16x8 a = *(const bf16x8*)&hread[rb][(abase + 32 * j) & 511];
            c0c = __builtin_amdgcn_mfma_f32_16x16x32_bf16(a, wf0[j], c0c, 0, 0, 0);
            c1c = __builtin_amdgcn_mfma_f32_16x16x32_bf16(a, wf1[j], c1c, 0, 0, 0);
        }

        // --- tanh -> local mailbox ship h(t) (tag t+1, parity wb) -> states
        if (comp) {
            const float hAv = fast_tanh(xAv + acc0[0] + c0a[0] + c0b[0] + c0c[0] + bA);
            const float hBv = fast_tanh(xBv + acc1[0] + c1a[0] + c1b[0] + c1c[0] + bB);
            volatile u64* ms = (volatile u64*)(mboxL + (size_t)(((b << 1) | wb) * 4 + p) * 128);
            const u64 tag = (u64)(unsigned)(t + 1) << 32;
            union { float f; unsigned u; } cA, cB;
            cA.f = hAv; cB.f = hBv;
            ms[wave * 32 + col]      = tag | cA.u;   // plain store: stays in XCD L2
            ms[wave * 32 + col + 16] = tag | cB.u;
            stA[(size_t)t * 512]      = hAv;
            stA[(size_t)t * 512 + 16] = hBv;
            hist[rt][hA] = hAv;  hread[wb][hA] = (__bf16)(ppA + k0 * hAv);
            hist[rt][hB] = hBv;  hread[wb][hB] = (__bf16)(ppB + k0 * hBv);
        }
        // --- wave0: deposit xp(t+1) (compiler inserts vmcnt wait for nx here)
        if (wave == 0) {
            xpb[wb][lane * 2]     = nx.x;
            xpb[wb][lane * 2 + 1] = nx.y;
        }
    }

    // final state output: each block writes its OWN slice of h(1023) (row 3)
    float* out2 = out + (size_t)32 * 1024 * 512 + (size_t)b * 512;
    if (comp) {
        out2[hA] = hist[3][hA];
        out2[hB] = hist[3][hB];
    }
}

// ---------------------------------------------------------------------------
extern "C" void kernel_launch(void* const* d_in, const int* in_sizes, int n_in,
                              void* d_out, int out_size, void* d_ws, size_t ws_size,
                              hipStream_t stream) {
    const float* x    = (const float*)d_in[0];   // [32,1024,512]
    const float* Wih  = (const float*)d_in[1];   // [512,512]
    const float* Whh  = (const float*)d_in[2];   // [512,512]
    const float* bih  = (const float*)d_in[3];   // [512]
    const float* bhh  = (const float*)d_in[4];   // [512]
    const float* kern = (const float*)d_in[5];   // [4]
    float* out = (float*)d_out;

    // mailboxes: 2 x (32 batches x 2 parity x 4 slices x 128 tagged u64) = 512 KB.
    // mboxG: agent-scope fallback (correctness). mboxL: XCD-local fast path.
    // No init needed: exact tag match; harness re-poison can't match a tag.
    u64* mboxG = (u64*)d_ws;
    u64* mboxL = mboxG + 32 * 2 * 4 * 128;

    dim3 g1(512, 8, 1);
    xproj_gemm_kernel<<<g1, 256, 0, stream>>>(x, Wih, bih, out);
    lagrange_rnn_kernel<<<128, 256, 0, stream>>>(Whh, bhh, kern, out, mboxG, mboxL);
}

// Round 3
// 2187.438 us; speedup vs baseline: 2.0450x; 2.0450x over previous
//
#include <hip/hip_runtime.h>

typedef __bf16 bf16x8 __attribute__((ext_vector_type(8)));
typedef float  f32x4  __attribute__((ext_vector_type(4)));
typedef unsigned long long u64;
typedef u64 u64x2 __attribute__((ext_vector_type(2)));

#define AGENT __HIP_MEMORY_SCOPE_AGENT

__device__ __forceinline__ float fast_tanh(float x) {
    float e = __expf(2.0f * x);
    return 1.0f - 2.0f * __builtin_amdgcn_rcpf(e + 1.0f);
}

// Raw barrier: drain ONLY LDS ops (cross-wave hread/hist visibility); global
// loads/stores stay in flight across the barrier.
__device__ __forceinline__ void lds_barrier() {
    asm volatile("s_waitcnt lgkmcnt(0)" ::: "memory");
    __builtin_amdgcn_s_barrier();
}

// SE-scope (L1-bypass, L2-served) 16B poll load. vmcnt(0) is safe: polling
// waves have no other outstanding vmem by design.
__device__ __forceinline__ u64x2 poll_ld(const u64* p) {
    u64x2 v;
    asm volatile("global_load_dwordx4 %0, %1, off sc0\n\t"
                 "s_waitcnt vmcnt(0)"
                 : "=v"(v) : "v"(p));
    return v;
}

// Plain write-back store (NO sc flags): lands in this XCD's L2 and stays
// there, visible to same-XCD sc0 loads. (volatile stores compile to sc0 sc1 =
// full cache bypass -> HBM, which is what broke round 2: consumers spun on a
// permanently-stale L2 line. WRITE_SIZE confirmed: +134 MB of mbox writes.)
__device__ __forceinline__ void mbox_st(u64* p, u64 v) {
    asm volatile("global_store_dwordx2 %0, %1, off" :: "v"(p), "v"(v) : "memory");
}

// ---------------------------------------------------------------------------
// Kernel 1: xproj = x @ Wih^T + bih -> fp32 into d_out's states region.
// ---------------------------------------------------------------------------
__global__ __launch_bounds__(256) void xproj_gemm_kernel(
    const float* __restrict__ x, const float* __restrict__ Wih,
    const float* __restrict__ bih, float* __restrict__ out)
{
    __shared__ __bf16 Ash[64][72];
    __shared__ __bf16 Bsh[64][72];

    const int tid  = threadIdx.x;
    const int wave = tid >> 6, lane = tid & 63;
    const int col  = lane & 15, kq = lane >> 4;
    const int bt0  = blockIdx.x * 64;
    const int h0   = blockIdx.y * 64;

    f32x4 acc[4];
#pragma unroll
    for (int nt = 0; nt < 4; ++nt) acc[nt] = (f32x4){0.f, 0.f, 0.f, 0.f};

    const int r  = tid >> 2;
    const int cb = (tid & 3) * 16;

    for (int k0 = 0; k0 < 512; k0 += 64) {
        const float* ax = x   + (size_t)(bt0 + r) * 512 + k0 + cb;
        const float* bx = Wih + (size_t)(h0  + r) * 512 + k0 + cb;
#pragma unroll
        for (int j = 0; j < 4; ++j) {
            const float4 av = ((const float4*)ax)[j];
            const float4 bv = ((const float4*)bx)[j];
            const int c = cb + 4 * j;
            Ash[r][c+0]=(__bf16)av.x; Ash[r][c+1]=(__bf16)av.y;
            Ash[r][c+2]=(__bf16)av.z; Ash[r][c+3]=(__bf16)av.w;
            Bsh[r][c+0]=(__bf16)bv.x; Bsh[r][c+1]=(__bf16)bv.y;
            Bsh[r][c+2]=(__bf16)bv.z; Bsh[r][c+3]=(__bf16)bv.w;
        }
        __syncthreads();
#pragma unroll
        for (int kt = 0; kt < 2; ++kt) {
            bf16x8 a = *(const bf16x8*)&Ash[wave * 16 + col][kt * 32 + kq * 8];
#pragma unroll
            for (int nt = 0; nt < 4; ++nt) {
                bf16x8 bb = *(const bf16x8*)&Bsh[nt * 16 + col][kt * 32 + kq * 8];
                acc[nt] = __builtin_amdgcn_mfma_f32_16x16x32_bf16(a, bb, acc[nt], 0, 0, 0);
            }
        }
        __syncthreads();
    }
#pragma unroll
    for (int nt = 0; nt < 4; ++nt) {
        const float bv = bih[h0 + nt * 16 + col];
#pragma unroll
        for (int reg = 0; reg < 4; ++reg) {
            const int m = bt0 + wave * 16 + kq * 4 + reg;
            out[(size_t)m * 512 + h0 + nt * 16 + col] = acc[nt][reg] + bv;
        }
    }
}

// ---------------------------------------------------------------------------
// Kernel 2: recurrence. 128 blocks = 32 batches x 4 weight-stationary slices.
// Fast path: XCD-local mailbox (plain write-back stores + sc0 loads -> L2 RT).
// Safety net: wave0 posts the whole block's h(t-1) to an agent-scope global
// mailbox each step; pollers check it every 4th local miss — so a changed
// blockIdx->XCD mapping degrades speed (~round-1 level), never correctness.
// ---------------------------------------------------------------------------
__global__ __launch_bounds__(256) void lagrange_rnn_kernel(
    const float* __restrict__ Whh, const float* __restrict__ bhh,
    const float* __restrict__ kern, float* __restrict__ out,
    u64* __restrict__ mboxG, u64* __restrict__ mboxL)
{
    const int id   = blockIdx.x;                 // 0..127
    const int b    = (id & 7) + ((id >> 5) << 3);// batch 0..31 (group on one XCD)
    const int p    = (id >> 3) & 3;              // slice member 0..3
    const int tid  = threadIdx.x;
    const int wave = tid >> 6, lane = tid & 63;
    const int col  = lane & 15, kq = lane >> 4;

    __shared__ float  hist[4][512];    // circular h history, fp32
    __shared__ __bf16 hread[2][512];   // parity double-buffered MFMA A operand
    __shared__ float  xpb[2][128];     // parity double-buffered xp (wave0-fed)

    for (int i = tid; i < 2048; i += 256) ((float*)hist)[i] = 0.f;
    for (int i = tid; i < 512;  i += 256) { hread[0][i] = (__bf16)0.f; hread[1][i] = (__bf16)0.f; }

    // --- weight fragments, K-reordered: wf[j] <-> global K-tile (4p+j)&15
    const int hA = p * 128 + wave * 32 + col;
    const int hB = hA + 16;
    bf16x8 wf0[16], wf1[16];
#pragma unroll
    for (int j = 0; j < 16; ++j) {
        const int ktg = ((j + 4 * p) & 15) * 32 + kq * 8;
        const float* s0 = Whh + (size_t)hA * 512 + ktg;
        const float* s1 = Whh + (size_t)hB * 512 + ktg;
        const float4 a0 = *(const float4*)s0, a1 = *(const float4*)(s0 + 4);
        const float4 b0 = *(const float4*)s1, b1 = *(const float4*)(s1 + 4);
        bf16x8 w;
        w[0]=(__bf16)a0.x; w[1]=(__bf16)a0.y; w[2]=(__bf16)a0.z; w[3]=(__bf16)a0.w;
        w[4]=(__bf16)a1.x; w[5]=(__bf16)a1.y; w[6]=(__bf16)a1.z; w[7]=(__bf16)a1.w;
        wf0[j] = w;
        w[0]=(__bf16)b0.x; w[1]=(__bf16)b0.y; w[2]=(__bf16)b0.z; w[3]=(__bf16)b0.w;
        w[4]=(__bf16)b1.x; w[5]=(__bf16)b1.y; w[6]=(__bf16)b1.z; w[7]=(__bf16)b1.w;
        wf1[j] = w;
    }
    const float k0 = kern[0], k1 = kern[1], k2 = kern[2], k3 = kern[3];
    const float bA = bhh[hA], bB = bhh[hB];
    float* stA = out + (size_t)b * 1024 * 512 + hA;
    // wave0's xp source: the block's contiguous 128-slice [p*128, p*128+128)
    const float* xsrc = out + (size_t)b * 1024 * 512 + p * 128 + lane * 2;
    const int peer = (p + wave) & 3;              // waves 1..3 poll this peer
    const int j0 = peer * 128 + lane * 2;
    const bool comp = (lane < 16);
    const int abase = p * 128 + kq * 8;           // j-th A addr = (abase + 32j) & 511
    const int xslot = wave * 32 + col;            // xp LDS slot for this comp lane

    if (wave == 0) {                              // preload xp(0)
        const float2 x0 = *(const float2*)xsrc;
        xpb[0][lane * 2] = x0.x; xpb[0][lane * 2 + 1] = x0.y;
    }
    __syncthreads();

    for (int t = 0; t < 1024; ++t) {
        const int rb = t & 1, wb = rb ^ 1;
        const int rt = t & 3;
        const int rm1 = (t + 3) & 3, rm2 = (t + 2) & 3, rm3 = (t + 1) & 3;

        // --- wave0: issue xp(t+1) prefetch (drained only at bottom deposit)
        float2 nx = {0.f, 0.f};
        if (wave == 0) nx = *(const float2*)(xsrc + (size_t)(t + 1) * 512);

        lds_barrier();   // barA: prev-step LDS deposits visible (lgkm only)

        if (wave == 0) {
            // --- global fallback post first (fire-and-forget, off critical path)
            u64* mg = mboxG + (size_t)(((b << 1) | rb) * 4 + p) * 128;
            union { float f; unsigned u; } a0, a1;
            a0.f = hist[rm1][p * 128 + lane * 2];
            a1.f = hist[rm1][p * 128 + lane * 2 + 1];
            const u64 tg = (u64)(unsigned)t << 32;
            __hip_atomic_store(&mg[lane * 2],     tg | a0.u, __ATOMIC_RELAXED, AGENT);
            __hip_atomic_store(&mg[lane * 2 + 1], tg | a1.u, __ATOMIC_RELAXED, AGENT);
        }

        // --- phase 1: own-K MFMAs (j=0..3) — operands produced locally last step
        f32x4 acc0 = (f32x4){0,0,0,0}, acc1 = (f32x4){0,0,0,0};
#pragma unroll
        for (int j = 0; j < 4; ++j) {
            bf16x8 a = *(const bf16x8*)&hread[rb][(abase + 32 * j) & 511];
            acc0 = __builtin_amdgcn_mfma_f32_16x16x32_bf16(a, wf0[j], acc0, 0, 0, 0);
            acc1 = __builtin_amdgcn_mfma_f32_16x16x32_bf16(a, wf1[j], acc1, 0, 0, 0);
        }

        if (wave != 0 && t) {
            // --- poll peer's h(t-1): local L2 mailbox, agent fallback every 4th miss
            const unsigned want = (unsigned)t;
            const u64* ml = mboxL + (size_t)(((b << 1) | rb) * 4 + peer) * 128 + lane * 2;
            const u64* mg = mboxG + (size_t)(((b << 1) | rb) * 4 + peer) * 128 + lane * 2;
            u64x2 v = poll_ld(ml);
            int k = 0;
            while ((unsigned)(v[0] >> 32) != want || (unsigned)(v[1] >> 32) != want) {
                if ((++k & 3) == 0) {
                    const u64 g0 = __hip_atomic_load(&mg[0], __ATOMIC_RELAXED, AGENT);
                    const u64 g1 = __hip_atomic_load(&mg[1], __ATOMIC_RELAXED, AGENT);
                    if ((unsigned)(g0 >> 32) == want && (unsigned)(g1 >> 32) == want) {
                        v[0] = g0; v[1] = g1; break;
                    }
                }
                v = poll_ld(ml);
            }
            union { unsigned u; float f; } d0, d1;
            d0.u = (unsigned)v[0]; d1.u = (unsigned)v[1];
            const float q0 = k1 * hist[rm2][j0]     + k2 * hist[rm3][j0]     + k3 * hist[rt][j0];
            const float q1 = k1 * hist[rm2][j0 + 1] + k2 * hist[rm3][j0 + 1] + k3 * hist[rt][j0 + 1];
            hread[rb][j0]     = (__bf16)(q0 + k0 * d0.f);
            hread[rb][j0 + 1] = (__bf16)(q1 + k0 * d1.f);
            hist[rm1][j0]     = d0.f;
            hist[rm1][j0 + 1] = d1.f;
        }

        lds_barrier();   // barB: poll deposits visible (lgkm only)

        // --- xp read + Lagrange partial for own hread(t+1)
        float xAv = 0.f, xBv = 0.f, ppA = 0.f, ppB = 0.f;
        if (comp) {
            xAv = xpb[rb][xslot];
            xBv = xpb[rb][xslot + 16];
            ppA = k1 * hist[rm1][hA] + k2 * hist[rm2][hA] + k3 * hist[rm3][hA];
            ppB = k1 * hist[rm1][hB] + k2 * hist[rm2][hB] + k3 * hist[rm3][hB];
        }

        // --- phase 2: peer-K MFMAs (j=4..15), 6 fresh chains (4-deep) for ILP
        f32x4 c0a = (f32x4){0,0,0,0}, c0b = (f32x4){0,0,0,0}, c0c = (f32x4){0,0,0,0};
        f32x4 c1a = (f32x4){0,0,0,0}, c1b = (f32x4){0,0,0,0}, c1c = (f32x4){0,0,0,0};
#pragma unroll
        for (int j = 4; j < 8; ++j) {
            bf16x8 a = *(const bf16x8*)&hread[rb][(abase + 32 * j) & 511];
            c0a = __builtin_amdgcn_mfma_f32_16x16x32_bf16(a, wf0[j], c0a, 0, 0, 0);
            c1a = __builtin_amdgcn_mfma_f32_16x16x32_bf16(a, wf1[j], c1a, 0, 0, 0);
        }
#pragma unroll
        for (int j = 8; j < 12; ++j) {
            bf16x8 a = *(const bf16x8*)&hread[rb][(abase + 32 * j) & 511];
            c0b = __builtin_amdgcn_mfma_f32_16x16x32_bf16(a, wf0[j], c0b, 0, 0, 0);
            c1b = __builtin_amdgcn_mfma_f32_16x16x32_bf16(a, wf1[j], c1b, 0, 0, 0);
        }
#pragma unroll
        for (int j = 12; j < 16; ++j) {
            bf16x8 a = *(const bf16x8*)&hread[rb][(abase + 32 * j) & 511];
            c0c = __builtin_amdgcn_mfma_f32_16x16x32_bf16(a, wf0[j], c0c, 0, 0, 0);
            c1c = __builtin_amdgcn_mfma_f32_16x16x32_bf16(a, wf1[j], c1c, 0, 0, 0);
        }

        // --- tanh -> local mailbox ship h(t) (tag t+1, parity wb) -> states
        if (comp) {
            const float hAv = fast_tanh(xAv + acc0[0] + c0a[0] + c0b[0] + c0c[0] + bA);
            const float hBv = fast_tanh(xBv + acc1[0] + c1a[0] + c1b[0] + c1c[0] + bB);
            u64* ms = mboxL + (size_t)(((b << 1) | wb) * 4 + p) * 128;
            const u64 tag = (u64)(unsigned)(t + 1) << 32;
            union { float f; unsigned u; } cA, cB;
            cA.f = hAv; cB.f = hBv;
            mbox_st(&ms[wave * 32 + col],      tag | cA.u);  // plain: stays in XCD L2
            mbox_st(&ms[wave * 32 + col + 16], tag | cB.u);
            stA[(size_t)t * 512]      = hAv;
            stA[(size_t)t * 512 + 16] = hBv;
            hist[rt][hA] = hAv;  hread[wb][hA] = (__bf16)(ppA + k0 * hAv);
            hist[rt][hB] = hBv;  hread[wb][hB] = (__bf16)(ppB + k0 * hBv);
        }
        // --- wave0: deposit xp(t+1) (compiler inserts vmcnt wait for nx here)
        if (wave == 0) {
            xpb[wb][lane * 2]     = nx.x;
            xpb[wb][lane * 2 + 1] = nx.y;
        }
    }

    // final state output: each block writes its OWN slice of h(1023) (row 3)
    float* out2 = out + (size_t)32 * 1024 * 512 + (size_t)b * 512;
    if (comp) {
        out2[hA] = hist[3][hA];
        out2[hB] = hist[3][hB];
    }
}

// ---------------------------------------------------------------------------
extern "C" void kernel_launch(void* const* d_in, const int* in_sizes, int n_in,
                              void* d_out, int out_size, void* d_ws, size_t ws_size,
                              hipStream_t stream) {
    const float* x    = (const float*)d_in[0];   // [32,1024,512]
    const float* Wih  = (const float*)d_in[1];   // [512,512]
    const float* Whh  = (const float*)d_in[2];   // [512,512]
    const float* bih  = (const float*)d_in[3];   // [512]
    const float* bhh  = (const float*)d_in[4];   // [512]
    const float* kern = (const float*)d_in[5];   // [4]
    float* out = (float*)d_out;

    // mailboxes: 2 x (32 batches x 2 parity x 4 slices x 128 tagged u64) = 512 KB.
    // mboxG: agent-scope fallback (correctness). mboxL: XCD-local fast path.
    // No init needed: exact tag match; harness re-poison can't match a tag.
    u64* mboxG = (u64*)d_ws;
    u64* mboxL = mboxG + 32 * 2 * 4 * 128;

    dim3 g1(512, 8, 1);
    xproj_gemm_kernel<<<g1, 256, 0, stream>>>(x, Wih, bih, out);
    lagrange_rnn_kernel<<<128, 256, 0, stream>>>(Whh, bhh, kern, out, mboxG, mboxL);
}